// Round 2
// baseline (399.289 us; speedup 1.0000x reference)
//
#include <hip/hip_runtime.h>

// Problem constants (fixed by the reference setup)
#define T_ 4
#define N_ 100000
#define G_ 128
#define R_ 4
#define B_ 4096
#define K_ 32
#define I_ 128
#define BB 8           // b-rows per block (amortizes W reads)

// out[t,b,i] = sum_r sum_g mean[t,r,b,g] * W[r,g,i]
// mean[t,r,b,g] = (sum_k mask * E[t, idx[t,r,b,k], g]) / max(sum_k mask, 1)
__global__ __launch_bounds__(128) void static_influence_kernel(
    const float* __restrict__ E,     // [T,N,G]
    const float* __restrict__ W,     // [R,G,I]
    const int*   __restrict__ idx,   // [T,R,B,K]
    const int*   __restrict__ msk,   // [T,R,B,K] (0/1)
    float*       __restrict__ out)   // [T,B,I] flat
{
    const int tid = threadIdx.x;                 // g (gather) / i (matmul) channel
    const int blk = blockIdx.x;                  // t * (B/BB) + btile
    const int t  = blk / (B_ / BB);
    const int b0 = (blk % (B_ / BB)) * BB;

    __shared__ float mean_s[BB][G_];

    float acc[BB];
#pragma unroll
    for (int bb = 0; bb < BB; ++bb) acc[bb] = 0.f;

    const float* __restrict__ Et = E + (size_t)t * N_ * G_;

    for (int r = 0; r < R_; ++r) {
        // ---- masked neighbor means for BB rows ----
        for (int bb = 0; bb < BB; ++bb) {
            const int base = (((t * R_ + r) * B_) + (b0 + bb)) * K_;
            float s = 0.f;
            float cnt = 0.f;
#pragma unroll
            for (int k = 0; k < K_; ++k) {
                const int   id = idx[base + k];
                const float m  = (msk[base + k] != 0) ? 1.0f : 0.0f;
                s   += m * Et[(size_t)id * G_ + tid];
                cnt += m;
            }
            mean_s[bb][tid] = s / fmaxf(cnt, 1.0f);
        }
        __syncthreads();

        // ---- out[t,b,i] += sum_g mean[g] * W[r,g,i] ----
        const float* __restrict__ Wr = W + r * G_ * I_;
#pragma unroll 8
        for (int g = 0; g < G_; ++g) {
            const float w = Wr[g * I_ + tid];      // coalesced, L2-resident
#pragma unroll
            for (int bb = 0; bb < BB; ++bb)
                acc[bb] += mean_s[bb][g] * w;       // LDS broadcast
        }
        __syncthreads();
    }

#pragma unroll
    for (int bb = 0; bb < BB; ++bb)
        out[((size_t)t * B_ + (b0 + bb)) * I_ + tid] = acc[bb];
}

extern "C" void kernel_launch(void* const* d_in, const int* in_sizes, int n_in,
                              void* d_out, int out_size, void* d_ws, size_t ws_size,
                              hipStream_t stream) {
    const float* E   = (const float*)d_in[0];   // embeddings [T,N,G] f32
    const float* W   = (const float*)d_in[1];   // weights [R,G,I] f32
    const int*   idx = (const int*)d_in[2];     // neighbor_idx [T,R,B,K] i32
    const int*   msk = (const int*)d_in[3];     // neighbor_mask [T,R,B,K] i32 (bool)
    // d_in[4] = train_year scalar (compile-time constant here)
    float* out = (float*)d_out;                 // [T,B,I] f32 flat

    dim3 grid(T_ * (B_ / BB));
    dim3 block(128);
    hipLaunchKernelGGL(static_influence_kernel, grid, block, 0, stream,
                       E, W, idx, msk, out);
}

// Round 3
// 392.592 us; speedup vs baseline: 1.0171x; 1.0171x over previous
//
#include <hip/hip_runtime.h>

// Problem constants (fixed by the reference setup)
#define T_ 4
#define N_ 100000
#define G_ 128
#define R_ 4
#define B_ 4096
#define K_ 32
#define I_ 128
#define BB 8           // b-rows per block

// out[t,b,i] = sum_r sum_g mean[t,r,b,g] * W[r,g,i]
// mean[t,r,b,g] = (sum_k mask * E[t, idx[t,r,b,k], g]) / max(sum_k mask, 1)
//
// Block = 256 threads (4 waves), handles 8 b-rows of one t.
// Gather: lane owns (row = 2*wave + lane/32, g = (lane&31)*4 .. +3), float4 loads:
//         one wave instruction fetches 1024B = two full 512B embedding rows.
// Matmul: thread-set (tid>>7) owns 4 b-rows; means read from LDS (wave-uniform
//         broadcast), W coalesced + L2-resident.
__global__ __launch_bounds__(256) void static_influence_kernel(
    const float* __restrict__ E,     // [T,N,G]
    const float* __restrict__ W,     // [R,G,I]
    const int*   __restrict__ idx,   // [T,R,B,K]
    const int*   __restrict__ msk,   // [T,R,B,K] (0/1)
    float*       __restrict__ out)   // [T,B,I] flat
{
    const int tid = threadIdx.x;
    const int blk = blockIdx.x;
    const int t   = blk / (B_ / BB);
    const int b0  = (blk % (B_ / BB)) * BB;

    __shared__ float mean_s[BB][G_];     // 4 KB
    __shared__ int   idxm_s[BB * K_];    // 1 KB: id | (mask<<31)

    const int wave = tid >> 6;
    const int lane = tid & 63;
    const int half = lane >> 5;
    const int gl   = lane & 31;          // gather g-chunk: g = gl*4 .. gl*4+3
    const int bbg  = 2 * wave + half;    // gather row owned by this lane

    const int iset = tid >> 7;           // matmul row-set: 0 or 1
    const int i    = tid & 127;          // output channel

    float acc0 = 0.f, acc1 = 0.f, acc2 = 0.f, acc3 = 0.f;

    const float* __restrict__ Et = E + (size_t)t * N_ * G_;

    for (int r = 0; r < R_; ++r) {
        // ---- stage idx+mask (packed) for the 8 rows: one coalesced load each ----
        {
            const int base = ((t * R_ + r) * B_ + b0) * K_;   // 256 ints
            const int v = idx[base + tid];
            const int m = msk[base + tid];
            idxm_s[tid] = m ? (v | 0x80000000) : v;           // idx < 2^17, sign bit free
        }
        __syncthreads();

        // ---- masked neighbor sum for (bbg, 4 g's), all k ----
        float4 s4 = make_float4(0.f, 0.f, 0.f, 0.f);
        float  cnt = 0.f;
#pragma unroll 8
        for (int k = 0; k < K_; ++k) {
            const int   v  = idxm_s[bbg * K_ + k];            // 2-way LDS broadcast
            const int   id = v & 0x7FFFFFFF;
            const float fm = (v < 0) ? 1.0f : 0.0f;
            const float4 e4 = *reinterpret_cast<const float4*>(Et + (size_t)id * G_ + gl * 4);
            s4.x += fm * e4.x;  s4.y += fm * e4.y;
            s4.z += fm * e4.z;  s4.w += fm * e4.w;
            cnt  += fm;
        }
        const float inv = 1.0f / fmaxf(cnt, 1.0f);
        *reinterpret_cast<float4*>(&mean_s[bbg][gl * 4]) =
            make_float4(s4.x * inv, s4.y * inv, s4.z * inv, s4.w * inv);
        __syncthreads();

        // ---- acc[iset*4+j] += sum_g mean[bbm+j][g] * Wr[g][i] ----
        const float* __restrict__ Wr = W + r * G_ * I_;
        const int bbm = iset * 4;
#pragma unroll 2
        for (int g = 0; g < G_; g += 4) {
            const float w0 = Wr[(g + 0) * I_ + i];
            const float w1 = Wr[(g + 1) * I_ + i];
            const float w2 = Wr[(g + 2) * I_ + i];
            const float w3 = Wr[(g + 3) * I_ + i];
            const float4 m0 = *reinterpret_cast<const float4*>(&mean_s[bbm + 0][g]);
            const float4 m1 = *reinterpret_cast<const float4*>(&mean_s[bbm + 1][g]);
            const float4 m2 = *reinterpret_cast<const float4*>(&mean_s[bbm + 2][g]);
            const float4 m3 = *reinterpret_cast<const float4*>(&mean_s[bbm + 3][g]);
            acc0 += m0.x * w0 + m0.y * w1 + m0.z * w2 + m0.w * w3;
            acc1 += m1.x * w0 + m1.y * w1 + m1.z * w2 + m1.w * w3;
            acc2 += m2.x * w0 + m2.y * w1 + m2.z * w2 + m2.w * w3;
            acc3 += m3.x * w0 + m3.y * w1 + m3.z * w2 + m3.w * w3;
        }
        __syncthreads();
    }

    const size_t ob = ((size_t)t * B_ + b0 + iset * 4) * I_ + i;
    out[ob + 0 * I_] = acc0;
    out[ob + 1 * I_] = acc1;
    out[ob + 2 * I_] = acc2;
    out[ob + 3 * I_] = acc3;
}

extern "C" void kernel_launch(void* const* d_in, const int* in_sizes, int n_in,
                              void* d_out, int out_size, void* d_ws, size_t ws_size,
                              hipStream_t stream) {
    const float* E   = (const float*)d_in[0];   // embeddings [T,N,G] f32
    const float* W   = (const float*)d_in[1];   // weights [R,G,I] f32
    const int*   idx = (const int*)d_in[2];     // neighbor_idx [T,R,B,K] i32
    const int*   msk = (const int*)d_in[3];     // neighbor_mask [T,R,B,K] i32
    float* out = (float*)d_out;                 // [T,B,I] f32 flat

    dim3 grid(T_ * (B_ / BB));
    dim3 block(256);
    hipLaunchKernelGGL(static_influence_kernel, grid, block, 0, stream,
                       E, W, idx, msk, out);
}